// Round 10
// baseline (11379.130 us; speedup 1.0000x reference)
//
#include <hip/hip_runtime.h>
#include <hip/hip_bf16.h>
#include <hip/hip_fp8.h>
#include <stdint.h>

#define NSTEP 64
#define BATCH 32
#define EMBED_D 1536
#define ACT_D 16
#define DETER 2048
#define STOCH 512
#define HIDDEN 1024
#define FEAT 2560
#define NBLK 256

typedef __attribute__((ext_vector_type(8))) short bf16x8;
typedef __attribute__((ext_vector_type(4))) float f32x4;

#define MFMA16 __builtin_amdgcn_mfma_f32_16x16x32_bf16
#define AGENT __HIP_MEMORY_SCOPE_AGENT
#define INV8 (1.0f / 1024.0f)

__device__ __forceinline__ float eluf(float x) { return x > 0.f ? x : expf(x) - 1.f; }
__device__ __forceinline__ float sigf(float x) { return 1.f / (1.f + expf(-x)); }
__device__ __forceinline__ unsigned short f2bf(float f) {
    __hip_bfloat16 h = __float2bfloat16(f);
    return __builtin_bit_cast(unsigned short, h);
}
__device__ __forceinline__ float bf2f(unsigned short u) {
    unsigned v = ((unsigned)u) << 16;
    return __builtin_bit_cast(float, v);
}

// ---- fp8 e4m3 encode/decode (round-7 proven)
template <int SEL>
__device__ __forceinline__ float fp8_to_f32(unsigned u) {
#if __has_builtin(__builtin_amdgcn_cvt_f32_fp8)
    return __builtin_amdgcn_cvt_f32_fp8(u, SEL);
#else
    __hip_fp8_e4m3 q; q.__x = (unsigned char)(u >> (SEL * 8));
    return (float)q;
#endif
}
__device__ __forceinline__ unsigned char f32_to_fp8(float x) {
    x = fminf(fmaxf(x, -448.f), 448.f);
#if __has_builtin(__builtin_amdgcn_cvt_pk_fp8_f32)
    int r = __builtin_amdgcn_cvt_pk_fp8_f32(x, x, 0, false);
    return (unsigned char)(r & 0xff);
#else
    __hip_fp8_e4m3 q(x);
    return q.__x;
#endif
}
// 8 fp8 bytes -> bf16x8 (value = w*1024; fold INV8 into f32 combine) — round-7 proven
__device__ __forceinline__ bf16x8 dq8(const unsigned char* p) {
    uint2 d = *reinterpret_cast<const uint2*>(p);
    union { unsigned short s[8]; bf16x8 o; } u;
    u.s[0] = f2bf(fp8_to_f32<0>(d.x)); u.s[1] = f2bf(fp8_to_f32<1>(d.x));
    u.s[2] = f2bf(fp8_to_f32<2>(d.x)); u.s[3] = f2bf(fp8_to_f32<3>(d.x));
    u.s[4] = f2bf(fp8_to_f32<0>(d.y)); u.s[5] = f2bf(fp8_to_f32<1>(d.y));
    u.s[6] = f2bf(fp8_to_f32<2>(d.y)); u.s[7] = f2bf(fp8_to_f32<3>(d.y));
    return u.o;
}

// ---- sc1 (agent-scope relaxed) store/load helpers — round-7 proven data plane
__device__ __forceinline__ void stc_u32(unsigned* p, unsigned v) {
    __hip_atomic_store(p, v, __ATOMIC_RELAXED, AGENT);
}
__device__ __forceinline__ void stc_u64(unsigned long long* p, unsigned long long v) {
    __hip_atomic_store(p, v, __ATOMIC_RELAXED, AGENT);
}
__device__ __forceinline__ unsigned long long ldc_u64(const unsigned long long* p) {
    return __hip_atomic_load(p, __ATOMIC_RELAXED, AGENT);
}
__device__ __forceinline__ float ldc_f32(const float* p) {
    return __hip_atomic_load(p, __ATOMIC_RELAXED, AGENT);
}
__device__ __forceinline__ int ldc_i32(const int* p) {
    return __hip_atomic_load(p, __ATOMIC_RELAXED, AGENT);
}
__device__ __forceinline__ void stc_i32(int* p, int v) {
    __hip_atomic_store(p, v, __ATOMIC_RELAXED, AGENT);
}
__device__ __forceinline__ bf16x8 ldc_bf8(const unsigned short* p) {
    union { unsigned long long q[2]; bf16x8 v; } u;
    u.q[0] = ldc_u64((const unsigned long long*)p);
    u.q[1] = ldc_u64((const unsigned long long*)(p + 4));
    return u.v;
}
__device__ __forceinline__ ushort4 ldc_us4(const unsigned short* p) {
    unsigned long long q = ldc_u64((const unsigned long long*)p);
    return __builtin_bit_cast(ushort4, q);
}

// ---- flag-tree grid barrier, 32-way replicated release
__device__ __forceinline__ void gbar3(int* flags, int* release, int epoch) {
    asm volatile("s_waitcnt vmcnt(0)" ::: "memory");
    __syncthreads();
    if (blockIdx.x == 0) {
        int tid = threadIdx.x;
        if (tid >= 1 && tid < NBLK) {
            while (ldc_i32(&flags[tid * 32]) < epoch) __builtin_amdgcn_s_sleep(4);
        }
        asm volatile("" ::: "memory");
        __syncthreads();
        if (tid < 32) stc_i32(&release[tid * 32], epoch);
    } else {
        if (threadIdx.x == 0) {
            stc_i32(&flags[blockIdx.x * 32], epoch);
            int* rel = &release[(blockIdx.x & 31) * 32];
            while (ldc_i32(rel) < epoch) __builtin_amdgcn_s_sleep(4);
        }
        asm volatile("" ::: "memory");
        __syncthreads();
    }
}

// ---------------- weight conversions: Wz,Wpo -> bf16 ; Wih,Whh,Wph -> fp8*1024
__global__ __launch_bounds__(256) void k_cvt_all(
    const float* __restrict__ wz, unsigned short* __restrict__ wz16,
    const float* __restrict__ wpo, unsigned short* __restrict__ wpo16,
    const float* __restrict__ wih, unsigned char* __restrict__ wih8,
    const float* __restrict__ whh, unsigned char* __restrict__ whh8,
    const float* __restrict__ wph, unsigned char* __restrict__ wph8)
{
    long long e = ((long long)blockIdx.x * 256 + threadIdx.x) * 4;
    if (e < 1572864) {
        const float* src; unsigned short* dst; long long off;
        if (e < 524288) { src = wz;  dst = wz16;  off = e; }
        else            { src = wpo; dst = wpo16; off = e - 524288; }
        float4 v = *reinterpret_cast<const float4*>(src + off);
        ushort4 o;
        o.x = f2bf(v.x); o.y = f2bf(v.y); o.z = f2bf(v.z); o.w = f2bf(v.w);
        *reinterpret_cast<ushort4*>(dst + off) = o;
    } else {
        long long f = e - 1572864;
        const float* src; unsigned char* dst; long long off;
        if (f < 6291456)        { src = wih; dst = wih8; off = f; }
        else if (f < 18874368)  { src = whh; dst = whh8; off = f - 6291456; }
        else if (f < 20971520)  { src = wph; dst = wph8; off = f - 18874368; }
        else return;
        float4 v = *reinterpret_cast<const float4*>(src + off);
        uchar4 o;
        o.x = f32_to_fp8(v.x * 1024.f);
        o.y = f32_to_fp8(v.y * 1024.f);
        o.z = f32_to_fp8(v.z * 1024.f);
        o.w = f32_to_fp8(v.w * 1024.f);
        *reinterpret_cast<uchar4*>(dst + off) = o;
    }
}

// ---------------- setup: unmasked bf16 h0/z0; flags+release zero
__global__ __launch_bounds__(256) void k_setup(
    const float* __restrict__ h0, const float* __restrict__ z0,
    unsigned short* __restrict__ h16init, unsigned short* __restrict__ z16init,
    int* __restrict__ flags)
{
    int gid = blockIdx.x * 256 + threadIdx.x;
    int idx = gid * 4;
    if (idx < BATCH * DETER) {
        float4 v = *reinterpret_cast<const float4*>(h0 + idx);
        ushort4 o;
        o.x = f2bf(v.x); o.y = f2bf(v.y); o.z = f2bf(v.z); o.w = f2bf(v.w);
        *reinterpret_cast<ushort4*>(h16init + idx) = o;
    } else if (idx < BATCH * DETER + BATCH * STOCH) {
        int zi = idx - BATCH * DETER;
        float4 v = *reinterpret_cast<const float4*>(z0 + zi);
        ushort4 o;
        o.x = f2bf(v.x); o.y = f2bf(v.y); o.z = f2bf(v.z); o.w = f2bf(v.w);
        *reinterpret_cast<ushort4*>(z16init + zi) = o;
    }
    if (gid < 9216) flags[gid] = 0;   // flags (8192 ints) + release (1024 ints)
}

// ---------------- preA[r][j] = b_z[j] + action[r]@Wa[j]  (K=16)
__global__ __launch_bounds__(256) void k_preA(
    const float* __restrict__ action, const float* __restrict__ Wa,
    const float* __restrict__ bz, float* __restrict__ preA)
{
    __shared__ float al[16];
    int r = blockIdx.x, t = threadIdx.x;
    if (t < 16) al[t] = action[r * 16 + t];
    __syncthreads();
#pragma unroll
    for (int c = 0; c < 4; ++c) {
        int j = t + c * 256;
        const float* wr = Wa + j * 16;
        float s = bz[j];
#pragma unroll
        for (int k = 0; k < 16; ++k) s += al[k] * wr[k];
        preA[(size_t)r * 1024 + j] = s;
    }
}

// ---------------- one-shot MFMA GEMM (f32 sources, bf16 staging)
__global__ __launch_bounds__(256) void gemm_mfma(
    const float* __restrict__ A, int lda,
    const float* __restrict__ B, int ldb,
    const float* __restrict__ bias,
    float* __restrict__ C, int ldc, int K)
{
    __shared__ unsigned short Alds[64 * 72];
    __shared__ unsigned short Blds[64 * 72];
    int t = threadIdx.x;
    int nb = blockIdx.x, mb = blockIdx.y;
    int w = t >> 6, l = t & 63, l15 = l & 15, kg = l >> 4;
    f32x4 acc[4] = {{0,0,0,0},{0,0,0,0},{0,0,0,0},{0,0,0,0}};
    int srow = t >> 2, skq = (t & 3) * 16;
    const float* Asrc = A + (size_t)(mb * 64 + srow) * lda + skq;
    const float* Bsrc = B + (size_t)(nb * 64 + srow) * ldb + skq;
    unsigned short* Adst = &Alds[srow * 72 + skq];
    unsigned short* Bdst = &Blds[srow * 72 + skq];
    for (int kt = 0; kt < K; kt += 64) {
        __syncthreads();
#pragma unroll
        for (int c = 0; c < 16; c += 4) {
            float4 va = *reinterpret_cast<const float4*>(Asrc + kt + c);
            float4 vb = *reinterpret_cast<const float4*>(Bsrc + kt + c);
            ushort4 oa, ob;
            oa.x = f2bf(va.x); oa.y = f2bf(va.y); oa.z = f2bf(va.z); oa.w = f2bf(va.w);
            ob.x = f2bf(vb.x); ob.y = f2bf(vb.y); ob.z = f2bf(vb.z); ob.w = f2bf(vb.w);
            *reinterpret_cast<ushort4*>(Adst + c) = oa;
            *reinterpret_cast<ushort4*>(Bdst + c) = ob;
        }
        __syncthreads();
#pragma unroll
        for (int ks = 0; ks < 2; ks++) {
            bf16x8 a = *reinterpret_cast<const bf16x8*>(&Alds[(w * 16 + l15) * 72 + ks * 32 + kg * 8]);
#pragma unroll
            for (int nt = 0; nt < 4; nt++) {
                bf16x8 b = *reinterpret_cast<const bf16x8*>(&Blds[(nt * 16 + l15) * 72 + ks * 32 + kg * 8]);
                acc[nt] = MFMA16(a, b, acc[nt], 0, 0, 0);
            }
        }
    }
#pragma unroll
    for (int nt = 0; nt < 4; nt++) {
        int n = nb * 64 + nt * 16 + l15;
        float bv = bias[n];
#pragma unroll
        for (int i = 0; i < 4; i++) {
            C[(size_t)(mb * 64 + w * 16 + kg * 4 + i) * ldc + n] = acc[nt][i] + bv;
        }
    }
}

// ---------------- row LN+elu in place (f32)
__global__ __launch_bounds__(256) void ln_elu_rows(
    float* __restrict__ X, const float* __restrict__ g, const float* __restrict__ bb)
{
    __shared__ float sbuf[256], qbuf[256];
    int r = blockIdx.x, t = threadIdx.x;
    float* row = X + (size_t)r * HIDDEN;
    float4 v = reinterpret_cast<const float4*>(row)[t];
    sbuf[t] = (v.x + v.y) + (v.z + v.w);
    qbuf[t] = (v.x * v.x + v.y * v.y) + (v.z * v.z + v.w * v.w);
    __syncthreads();
    for (int off = 128; off > 0; off >>= 1) {
        if (t < off) { sbuf[t] += sbuf[t + off]; qbuf[t] += qbuf[t + off]; }
        __syncthreads();
    }
    float mean = sbuf[0] / HIDDEN;
    float var = qbuf[0] / HIDDEN - mean * mean;
    float rstd = rsqrtf(var + 1e-5f);
    float4 gg = reinterpret_cast<const float4*>(g)[t];
    float4 bv = reinterpret_cast<const float4*>(bb)[t];
    float4 o;
    o.x = eluf((v.x - mean) * rstd * gg.x + bv.x);
    o.y = eluf((v.y - mean) * rstd * gg.y + bv.y);
    o.z = eluf((v.z - mean) * rstd * gg.z + bv.z);
    o.w = eluf((v.w - mean) * rstd * gg.w + bv.w);
    reinterpret_cast<float4*>(row)[t] = o;
}

__global__ __launch_bounds__(256) void k_copy_last(
    const float* __restrict__ feat63, const float* __restrict__ samp63,
    float* __restrict__ hlast, float* __restrict__ zlast)
{
    int i = blockIdx.x * 256 + threadIdx.x;
    if (i < BATCH * DETER) {
        int b = i / DETER, k = i % DETER;
        hlast[i] = feat63[(size_t)b * FEAT + k];
    }
    if (i < BATCH * STOCH) zlast[i] = samp63[i];
}

// ======================= persistent scan (plain launch, 1 block/CU) =======================
struct ScanArgs {
    const unsigned short *Wz16, *Wpo16;
    const unsigned char *Wih8, *Whh8, *Wph8;
    const float *bih, *bhh, *b_post;
    const float *ln_in_g, *ln_in_b, *ln_post_g, *ln_post_b;
    const float *h0;
    const uint8_t *reset;
    const float *noises;
    float *postsPreA, *priorsPreE, *samples, *feats;
    unsigned short *z16init, *h16init, *z16step, *h16step, *x2b;
    float *x2p;
    int *flags, *release;
};

// LN+elu+cvt fill of padded LDS tile from sc1-written global bf16 (round-7 proven)
__device__ __forceinline__ void ln_fill(unsigned short* Asm, const unsigned short* __restrict__ src,
                                        const float* __restrict__ g, const float* __restrict__ bb,
                                        const float* stat, int tid) {
    int row = tid & 31, kb = (tid >> 5) * 128;
    float mean = stat[row], rstd = stat[32 + row];
#pragma unroll 4
    for (int c = 0; c < 16; ++c) {
        int k = kb + c * 8;
        ushort4 u0 = ldc_us4(src + (size_t)row * 1024 + k);
        ushort4 u1 = ldc_us4(src + (size_t)row * 1024 + k + 4);
        float4 g0 = *reinterpret_cast<const float4*>(g + k);
        float4 g1 = *reinterpret_cast<const float4*>(g + k + 4);
        float4 b0 = *reinterpret_cast<const float4*>(bb + k);
        float4 b1 = *reinterpret_cast<const float4*>(bb + k + 4);
        ushort4 o0, o1;
        o0.x = f2bf(eluf((bf2f(u0.x) - mean) * rstd * g0.x + b0.x));
        o0.y = f2bf(eluf((bf2f(u0.y) - mean) * rstd * g0.y + b0.y));
        o0.z = f2bf(eluf((bf2f(u0.z) - mean) * rstd * g0.z + b0.z));
        o0.w = f2bf(eluf((bf2f(u0.w) - mean) * rstd * g0.w + b0.w));
        o1.x = f2bf(eluf((bf2f(u1.x) - mean) * rstd * g1.x + b1.x));
        o1.y = f2bf(eluf((bf2f(u1.y) - mean) * rstd * g1.y + b1.y));
        o1.z = f2bf(eluf((bf2f(u1.z) - mean) * rstd * g1.z + b1.z));
        o1.w = f2bf(eluf((bf2f(u1.w) - mean) * rstd * g1.w + b1.w));
        *reinterpret_cast<ushort4*>(Asm + row * 1032 + k) = o0;
        *reinterpret_cast<ushort4*>(Asm + row * 1032 + k + 4) = o1;
    }
}

__global__ __launch_bounds__(256, 1) void k_scan(ScanArgs a) {
    // 90112 B > 80 KiB forces 1 block/CU (LDS); grid 256 <= 256 CUs -> all co-resident.
    __shared__ char smem[90112];
    unsigned short* Asm = (unsigned short*)smem;       // 66048 B: 32 x 1032 bf16
    float* cbuf = (float*)(smem + 66048);              // 8192 B (2048 f32)
    float* stat = (float*)(smem + 66048 + 8192);       // 512 B

    const int bid = blockIdx.x;
    const int tid = threadIdx.x;
    const int w = tid >> 6, l = tid & 63, l15 = l & 15, kg = l >> 4;
    const bf16x8 z8v = {0,0,0,0,0,0,0,0};
    int epoch = 0;

    for (int t = 0; t < NSTEP; ++t) {
        const float* preA_t = a.postsPreA + (size_t)t * 32768;
        const float* preE_t = a.priorsPreE + (size_t)t * 32768;
        float* posts_t = a.postsPreA + (size_t)t * 32768;
        float* samples_t = a.samples + (size_t)t * 16384;
        float* feats_t = a.feats + (size_t)t * 81920;
        const float* featsPrev = a.feats + (size_t)(t - 1) * 81920;
        const unsigned short* z16prev = t ? (a.z16step + (size_t)(t - 1) * 16384) : a.z16init;
        const unsigned short* h16prev = t ? (a.h16step + (size_t)(t - 1) * 65536) : a.h16init;
        unsigned short* h16t = a.h16step + (size_t)t * 65536;
        unsigned short* x2bt = a.x2b + (size_t)t * 32768;
        float* x2pt = a.x2p + (size_t)t * 4096;

        // ========== P2 (merged x1+LN+gates+combine): blocks 0..127 ==========
        if (bid < 128) {
            // ---- x1 staging: Asm = preA + (m z) @ Wz16^T (bf16), all 1024 cols ----
            {
                bool m0 = a.reset[t * 32 + l15] == 0;
                bool m1 = a.reset[t * 32 + 16 + l15] == 0;
                const unsigned short* zp0 = z16prev + l15 * 512 + kg * 8;
                const unsigned short* zp1 = zp0 + 16 * 512;
#pragma unroll
                for (int chunk = 0; chunk < 4; ++chunk) {
                    f32x4 acc0[4], acc1[4];
#pragma unroll
                    for (int u = 0; u < 4; ++u) { acc0[u] = {0,0,0,0}; acc1[u] = {0,0,0,0}; }
#pragma unroll 4
                    for (int kf = 0; kf < 16; ++kf) {
                        bf16x8 a0 = ldc_bf8(zp0 + kf * 32);
                        bf16x8 a1 = ldc_bf8(zp1 + kf * 32);
                        if (!m0) a0 = z8v;
                        if (!m1) a1 = z8v;
#pragma unroll
                        for (int u = 0; u < 4; ++u) {
                            int jt = w * 16 + chunk * 4 + u;
                            bf16x8 b = *reinterpret_cast<const bf16x8*>(
                                a.Wz16 + (size_t)(jt * 16 + l15) * 512 + kf * 32 + kg * 8);
                            acc0[u] = MFMA16(a0, b, acc0[u], 0, 0, 0);
                            acc1[u] = MFMA16(a1, b, acc1[u], 0, 0, 0);
                        }
                    }
#pragma unroll
                    for (int u = 0; u < 4; ++u) {
                        int col = (w * 16 + chunk * 4 + u) * 16 + l15;
#pragma unroll
                        for (int i = 0; i < 4; ++i) {
                            int row0 = kg * 4 + i;
                            Asm[row0 * 1032 + col] = f2bf(acc0[u][i] + preA_t[row0 * 1024 + col]);
                            int row1 = 16 + kg * 4 + i;
                            Asm[row1 * 1032 + col] = f2bf(acc1[u][i] + preA_t[row1 * 1024 + col]);
                        }
                    }
                }
            }
            __syncthreads();
            // ---- in-block LN stats + LN+elu in place over Asm ----
            {
                int row = tid & 31, ch = tid >> 5;
                unsigned short* rp = Asm + row * 1032 + ch * 128;
                float s = 0.f, q = 0.f;
#pragma unroll 4
                for (int c = 0; c < 16; ++c) {
                    bf16x8 v8 = *reinterpret_cast<const bf16x8*>(rp + c * 8);
#pragma unroll
                    for (int e = 0; e < 8; ++e) {
                        float f = bf2f((unsigned short)v8[e]);
                        s += f; q += f * f;
                    }
                }
                cbuf[(row * 8 + ch) * 2] = s;
                cbuf[(row * 8 + ch) * 2 + 1] = q;
                __syncthreads();
                if (tid < 32) {
                    float ss = 0.f, qq = 0.f;
#pragma unroll
                    for (int i = 0; i < 8; ++i) {
                        ss += cbuf[(tid * 8 + i) * 2];
                        qq += cbuf[(tid * 8 + i) * 2 + 1];
                    }
                    float mean = ss * (1.f / 1024.f);
                    float var = qq * (1.f / 1024.f) - mean * mean;
                    stat[tid] = mean;
                    stat[32 + tid] = rsqrtf(var + 1e-5f);
                }
                __syncthreads();
                float mean = stat[row], rstd = stat[32 + row];
#pragma unroll 2
                for (int c = 0; c < 16; ++c) {
                    int k = ch * 128 + c * 8;
                    ushort4 u0 = *reinterpret_cast<const ushort4*>(Asm + row * 1032 + k);
                    ushort4 u1 = *reinterpret_cast<const ushort4*>(Asm + row * 1032 + k + 4);
                    float4 g0 = *reinterpret_cast<const float4*>(a.ln_in_g + k);
                    float4 g1 = *reinterpret_cast<const float4*>(a.ln_in_g + k + 4);
                    float4 b0 = *reinterpret_cast<const float4*>(a.ln_in_b + k);
                    float4 b1 = *reinterpret_cast<const float4*>(a.ln_in_b + k + 4);
                    ushort4 o0, o1;
                    o0.x = f2bf(eluf((bf2f(u0.x) - mean) * rstd * g0.x + b0.x));
                    o0.y = f2bf(eluf((bf2f(u0.y) - mean) * rstd * g0.y + b0.y));
                    o0.z = f2bf(eluf((bf2f(u0.z) - mean) * rstd * g0.z + b0.z));
                    o0.w = f2bf(eluf((bf2f(u0.w) - mean) * rstd * g0.w + b0.w));
                    o1.x = f2bf(eluf((bf2f(u1.x) - mean) * rstd * g1.x + b1.x));
                    o1.y = f2bf(eluf((bf2f(u1.y) - mean) * rstd * g1.y + b1.y));
                    o1.z = f2bf(eluf((bf2f(u1.z) - mean) * rstd * g1.z + b1.z));
                    o1.w = f2bf(eluf((bf2f(u1.w) - mean) * rstd * g1.w + b1.w));
                    *reinterpret_cast<ushort4*>(Asm + row * 1032 + k) = o0;
                    *reinterpret_cast<ushort4*>(Asm + row * 1032 + k + 4) = o1;
                }
            }
            __syncthreads();
            // ---- gates MFMA + GRU combine ----
            int j0 = bid * 16;
            bool isI = (w < 2);
            int mt = w & 1;
            f32x4 cr = {0,0,0,0}, cu = {0,0,0,0}, cn = {0,0,0,0};
            if (isI) {
                const unsigned short* ap = Asm + (mt * 16 + l15) * 1032 + kg * 8;
                const unsigned char* br = a.Wih8 + (size_t)(j0 + l15) * 1024 + kg * 8;
                const unsigned char* bu = br + (size_t)2048 * 1024;
                const unsigned char* bn = bu + (size_t)2048 * 1024;
#pragma unroll 8
                for (int ks = 0; ks < 32; ++ks) {
                    bf16x8 av = *reinterpret_cast<const bf16x8*>(ap + ks * 32);
                    cr = MFMA16(av, dq8(br + ks * 32), cr, 0, 0, 0);
                    cu = MFMA16(av, dq8(bu + ks * 32), cu, 0, 0, 0);
                    cn = MFMA16(av, dq8(bn + ks * 32), cn, 0, 0, 0);
                }
            } else {
                bool mh = a.reset[t * 32 + mt * 16 + l15] == 0;
                const unsigned short* hp = h16prev + (size_t)(mt * 16 + l15) * 2048 + kg * 8;
                const unsigned char* br = a.Whh8 + (size_t)(j0 + l15) * 2048 + kg * 8;
                const unsigned char* bu = br + (size_t)2048 * 2048;
                const unsigned char* bn = bu + (size_t)2048 * 2048;
#pragma unroll 8
                for (int ks = 0; ks < 64; ++ks) {
                    bf16x8 av = ldc_bf8(hp + ks * 32);
                    if (!mh) av = z8v;
                    cr = MFMA16(av, dq8(br + ks * 32), cr, 0, 0, 0);
                    cu = MFMA16(av, dq8(bu + ks * 32), cu, 0, 0, 0);
                    cn = MFMA16(av, dq8(bn + ks * 32), cn, 0, 0, 0);
                }
#pragma unroll
                for (int i = 0; i < 4; ++i) {
                    cbuf[((mt * 3 + 0) * 16 + kg * 4 + i) * 16 + l15] = cr[i];
                    cbuf[((mt * 3 + 1) * 16 + kg * 4 + i) * 16 + l15] = cu[i];
                    cbuf[((mt * 3 + 2) * 16 + kg * 4 + i) * 16 + l15] = cn[i];
                }
            }
            __syncthreads();
            if (isI) {
                int j = j0 + l15;
                float bihr = a.bih[j], bihu = a.bih[j + 2048], bihn = a.bih[j + 4096];
                float bhhr = a.bhh[j], bhhu = a.bhh[j + 2048], bhhn = a.bhh[j + 4096];
#pragma unroll
                for (int i = 0; i < 4; ++i) {
                    int b = mt * 16 + kg * 4 + i;
                    float gr = cr[i] * INV8 + bihr;
                    float gu = cu[i] * INV8 + bihu;
                    float gn = cn[i] * INV8 + bihn;
                    float hr = cbuf[((mt * 3 + 0) * 16 + kg * 4 + i) * 16 + l15] * INV8 + bhhr;
                    float hu = cbuf[((mt * 3 + 1) * 16 + kg * 4 + i) * 16 + l15] * INV8 + bhhu;
                    float hn = cbuf[((mt * 3 + 2) * 16 + kg * 4 + i) * 16 + l15] * INV8 + bhhn;
                    float r = sigf(gr + hr), u = sigf(gu + hu);
                    float cand = tanhf(gn + r * hn);
                    float m = a.reset[t * 32 + b] ? 0.f : 1.f;
                    float hpv = (t == 0) ? a.h0[(size_t)b * 2048 + j]
                                         : ldc_f32(featsPrev + (size_t)b * 2560 + j);
                    float hnew = (1.f - u) * cand + u * (m * hpv);
                    cbuf[1536 + b * 16 + l15] = hnew;
                }
            }
            __syncthreads();
            {
                int b = tid >> 3, c2 = (tid & 7) * 2;
                float h0v = cbuf[1536 + b * 16 + c2], h1v = cbuf[1536 + b * 16 + c2 + 1];
                int j = j0 + c2;
                union { float f[2]; unsigned long long u; } fu;
                fu.f[0] = h0v; fu.f[1] = h1v;
                stc_u64((unsigned long long*)(feats_t + (size_t)b * 2560 + j), fu.u);
                unsigned short g0 = f2bf(h0v), g1 = f2bf(h1v);
                stc_u32((unsigned*)(h16t + (size_t)b * 2048 + j),
                        (unsigned)g0 | ((unsigned)g1 << 16));
            }
        }
        epoch++; gbar3(a.flags, a.release, epoch);

        // ========== P3: x2 = preE + h' @ Wph^T  (64 blocks x 16 cols) ==========
        if (bid < 64) {
            int j0 = bid * 16;
            const unsigned short* A0 = h16t + l15 * 2048 + w * 512 + kg * 8;
            const unsigned short* A1 = A0 + 16 * 2048;
            const unsigned char* Bp = a.Wph8 + (size_t)(j0 + l15) * 2048 + w * 512 + kg * 8;
            f32x4 c0 = {0,0,0,0}, c1 = {0,0,0,0};
#pragma unroll 8
            for (int ks = 0; ks < 16; ++ks) {
                bf16x8 b = dq8(Bp + ks * 32);
                c0 = MFMA16(ldc_bf8(A0 + ks * 32), b, c0, 0, 0, 0);
                c1 = MFMA16(ldc_bf8(A1 + ks * 32), b, c1, 0, 0, 0);
            }
#pragma unroll
            for (int i = 0; i < 4; ++i) {
                cbuf[w * 512 + (kg * 4 + i) * 16 + l15] = c0[i];
                cbuf[w * 512 + (16 + kg * 4 + i) * 16 + l15] = c1[i];
            }
            __syncthreads();
            int r = tid >> 3, c2 = (tid & 7) * 2;
            int base = r * 16 + c2;
            float v0 = (cbuf[base] + cbuf[512 + base] + cbuf[1024 + base] + cbuf[1536 + base]) * INV8
                     + preE_t[r * 1024 + j0 + c2];
            float v1 = (cbuf[base + 1] + cbuf[512 + base + 1] + cbuf[1024 + base + 1] + cbuf[1536 + base + 1]) * INV8
                     + preE_t[r * 1024 + j0 + c2 + 1];
            unsigned short u0 = f2bf(v0), u1 = f2bf(v1);
            stc_u32((unsigned*)(x2bt + (size_t)r * 1024 + j0 + c2),
                    (unsigned)u0 | ((unsigned)u1 << 16));
            float w0 = bf2f(u0), w1 = bf2f(u1);
            float s = w0 + w1, q = w0 * w0 + w1 * w1;
            s += __shfl_xor(s, 1); q += __shfl_xor(q, 1);
            s += __shfl_xor(s, 2); q += __shfl_xor(q, 2);
            s += __shfl_xor(s, 4); q += __shfl_xor(q, 4);
            if ((tid & 7) == 0) {
                union { float f[2]; unsigned long long u; } pu;
                pu.f[0] = s; pu.f[1] = q;
                stc_u64((unsigned long long*)(x2pt + ((size_t)bid * 32 + r) * 2), pu.u);
            }
        }
        epoch++; gbar3(a.flags, a.release, epoch);

        // ========== P4: post MFMA + sample (32 blocks x 16 cols) ==========
        if (bid < 32) {
            int j0 = bid * 16;
            if (tid < 32) {
                float s = 0.f, q = 0.f;
                for (int i = 0; i < 64; ++i) {
                    union { unsigned long long u; float f[2]; } c;
                    c.u = ldc_u64((const unsigned long long*)(x2pt + (size_t)(i * 32 + tid) * 2));
                    s += c.f[0]; q += c.f[1];
                }
                float mean = s * (1.f / 1024.f);
                float var = q * (1.f / 1024.f) - mean * mean;
                stat[tid] = mean;
                stat[32 + tid] = rsqrtf(var + 1e-5f);
            }
            __syncthreads();
            ln_fill(Asm, x2bt, a.ln_post_g, a.ln_post_b, stat, tid);
            __syncthreads();
            int tile = w >> 1, mt = w & 1;
            const unsigned short* ap = Asm + (mt * 16 + l15) * 1032 + kg * 8;
            int n = (tile == 0) ? (j0 + l15) : (512 + j0 + l15);
            const unsigned short* Bp = a.Wpo16 + (size_t)n * 1024 + kg * 8;
            f32x4 c = {0,0,0,0};
#pragma unroll 8
            for (int ks = 0; ks < 32; ++ks) {
                c = MFMA16(*reinterpret_cast<const bf16x8*>(ap + ks * 32),
                           *reinterpret_cast<const bf16x8*>(Bp + ks * 32), c, 0, 0, 0);
            }
#pragma unroll
            for (int i = 0; i < 4; ++i)
                cbuf[(tile * 2 + mt) * 256 + (kg * 4 + i) * 16 + l15] = c[i];
            __syncthreads();
            int b = tid >> 3, c2 = (tid & 7) * 2;
            int j = j0 + c2;
            int ib = (b >> 4) * 256 + (b & 15) * 16;
            float pm0 = cbuf[ib + c2] + a.b_post[j];
            float pm1 = cbuf[ib + c2 + 1] + a.b_post[j + 1];
            float ps0 = cbuf[512 + ib + c2] + a.b_post[512 + j];
            float ps1 = cbuf[512 + ib + c2 + 1] + a.b_post[512 + j + 1];
            posts_t[(size_t)b * 1024 + j] = pm0;
            posts_t[(size_t)b * 1024 + j + 1] = pm1;
            posts_t[(size_t)b * 1024 + 512 + j] = ps0;
            posts_t[(size_t)b * 1024 + 512 + j + 1] = ps1;
            float sp0 = fmaxf(ps0, 0.f) + log1pf(expf(-fabsf(ps0)));
            float sp1 = fmaxf(ps1, 0.f) + log1pf(expf(-fabsf(ps1)));
            float n0v = a.noises[(size_t)t * 16384 + b * 512 + j];
            float n1v = a.noises[(size_t)t * 16384 + b * 512 + j + 1];
            float smp0 = pm0 + (sp0 + 0.1f) * n0v;
            float smp1 = pm1 + (sp1 + 0.1f) * n1v;
            samples_t[(size_t)b * 512 + j] = smp0;
            samples_t[(size_t)b * 512 + j + 1] = smp1;
            feats_t[(size_t)b * 2560 + 2048 + j] = smp0;
            feats_t[(size_t)b * 2560 + 2048 + j + 1] = smp1;
            unsigned short zs0 = f2bf(smp0), zs1 = f2bf(smp1);
            stc_u32((unsigned*)(a.z16step + (size_t)t * 16384 + (size_t)b * 512 + j),
                    (unsigned)zs0 | ((unsigned)zs1 << 16));
        }
        epoch++; gbar3(a.flags, a.release, epoch);
    }
}

// ws byte offsets
#define WS_WZ16    ((size_t)0)          // 1,048,576 (bf16)
#define WS_WIH8    ((size_t)1048576)    // 6,291,456 (fp8)
#define WS_WHH8    ((size_t)7340032)    // 12,582,912 (fp8)
#define WS_WPH8    ((size_t)19922944)   // 2,097,152 (fp8)
#define WS_WPO16   ((size_t)22020096)   // 2,097,152 (bf16)
#define WS_Z16INIT ((size_t)24117248)   // 32,768
#define WS_H16INIT ((size_t)24150016)   // 131,072
#define WS_Z16STEP ((size_t)24281088)   // 2,097,152
#define WS_H16STEP ((size_t)26378240)   // 8,388,608
#define WS_X2B     ((size_t)34766848)   // 4,194,304
#define WS_X2P     ((size_t)38961152)   // 1,048,576
#define WS_FLAGS   ((size_t)40009728)   // 32,768
#define WS_REL     ((size_t)40042496)   // 4,096
#define WS_PRX     WS_WIH8              // alias: fp8 weights dead after scan

extern "C" void kernel_launch(void* const* d_in, const int* in_sizes, int n_in,
                              void* d_out, int out_size, void* d_ws, size_t ws_size,
                              hipStream_t stream)
{
    (void)in_sizes; (void)n_in; (void)out_size; (void)ws_size;
    const float*   embed  = (const float*)d_in[0];
    const float*   action = (const float*)d_in[1];
    const uint8_t* reset  = (const uint8_t*)d_in[2];
    const float*   h0     = (const float*)d_in[3];
    const float*   z0     = (const float*)d_in[4];
    const float*   noises = (const float*)d_in[5];
    const float*   W_z    = (const float*)d_in[6];
    const float*   b_z    = (const float*)d_in[7];
    const float*   W_a    = (const float*)d_in[8];
    const float*   ln_in_g = (const float*)d_in[9];
    const float*   ln_in_b = (const float*)d_in[10];
    const float*   Wih    = (const float*)d_in[11];
    const float*   Whh    = (const float*)d_in[12];
    const float*   bih    = (const float*)d_in[13];
    const float*   bhh    = (const float*)d_in[14];
    const float*   W_ph   = (const float*)d_in[15];
    const float*   b_ph   = (const float*)d_in[16];
    const float*   W_pe   = (const float*)d_in[17];
    const float*   ln_post_g = (const float*)d_in[18];
    const float*   ln_post_b = (const float*)d_in[19];
    const float*   W_post = (const float*)d_in[20];
    const float*   b_post = (const float*)d_in[21];
    const float*   W_prh  = (const float*)d_in[22];
    const float*   b_prh  = (const float*)d_in[23];
    const float*   ln_pr_g = (const float*)d_in[24];
    const float*   ln_pr_b = (const float*)d_in[25];
    const float*   W_pr   = (const float*)d_in[26];
    const float*   b_pr   = (const float*)d_in[27];

    float* out     = (float*)d_out;
    float* priors  = out;                  // preE lives here during scan
    float* posts   = out + 2097152;        // preA lives here during scan
    float* samples = out + 4194304;
    float* feats   = out + 5242880;
    float* hlast   = out + 10485760;
    float* zlast   = out + 10551296;

    char* ws = (char*)d_ws;
    unsigned short* Wz16  = (unsigned short*)(ws + WS_WZ16);
    unsigned char*  Wih8  = (unsigned char*)(ws + WS_WIH8);
    unsigned char*  Whh8  = (unsigned char*)(ws + WS_WHH8);
    unsigned char*  Wph8  = (unsigned char*)(ws + WS_WPH8);
    unsigned short* Wpo16 = (unsigned short*)(ws + WS_WPO16);
    unsigned short* z16i  = (unsigned short*)(ws + WS_Z16INIT);
    unsigned short* h16i  = (unsigned short*)(ws + WS_H16INIT);
    unsigned short* z16s  = (unsigned short*)(ws + WS_Z16STEP);
    unsigned short* h16s  = (unsigned short*)(ws + WS_H16STEP);
    unsigned short* x2b   = (unsigned short*)(ws + WS_X2B);
    float*          x2p   = (float*)(ws + WS_X2P);
    int*            flags = (int*)(ws + WS_FLAGS);
    int*            release = (int*)(ws + WS_REL);
    float*          prx   = (float*)(ws + WS_PRX);

    dim3 blk(256);

    k_cvt_all<<<dim3(22016), blk, 0, stream>>>(W_z, Wz16, W_post, Wpo16,
                                               Wih, Wih8, Whh, Whh8, W_ph, Wph8);
    k_setup<<<dim3(80), blk, 0, stream>>>(h0, z0, h16i, z16i, flags);

    // preA -> posts region ; preE -> priors region
    k_preA<<<dim3(2048), blk, 0, stream>>>(action, W_a, b_z, posts);
    gemm_mfma<<<dim3(16, 32), blk, 0, stream>>>(embed, EMBED_D, W_pe, EMBED_D, b_ph,
                                                priors, HIDDEN, EMBED_D);

    ScanArgs sa;
    sa.Wz16 = Wz16; sa.Wpo16 = Wpo16;
    sa.Wih8 = Wih8; sa.Whh8 = Whh8; sa.Wph8 = Wph8;
    sa.bih = bih; sa.bhh = bhh; sa.b_post = b_post;
    sa.ln_in_g = ln_in_g; sa.ln_in_b = ln_in_b; sa.ln_post_g = ln_post_g; sa.ln_post_b = ln_post_b;
    sa.h0 = h0; sa.reset = reset; sa.noises = noises;
    sa.postsPreA = posts; sa.priorsPreE = priors; sa.samples = samples; sa.feats = feats;
    sa.z16init = z16i; sa.h16init = h16i; sa.z16step = z16s; sa.h16step = h16s;
    sa.x2b = x2b; sa.x2p = x2p;
    sa.flags = flags; sa.release = release;

    // Plain launch: grid (256) == CU count, 1 block/CU via LDS (90112 B > 80 KiB),
    // so all blocks are co-resident; hand-rolled barrier needs no cooperative API.
    k_scan<<<dim3(NBLK), blk, 0, stream>>>(sa);

    // prior chain
    gemm_mfma<<<dim3(16, 32), blk, 0, stream>>>(feats, FEAT, W_prh, DETER, b_prh,
                                                prx, HIDDEN, DETER);
    ln_elu_rows<<<dim3(2048), blk, 0, stream>>>(prx, ln_pr_g, ln_pr_b);
    gemm_mfma<<<dim3(16, 32), blk, 0, stream>>>(prx, HIDDEN, W_pr, HIDDEN, b_pr,
                                                priors, HIDDEN, HIDDEN);

    k_copy_last<<<dim3(256), blk, 0, stream>>>(
        feats + (size_t)(NSTEP - 1) * BATCH * FEAT,
        samples + (size_t)(NSTEP - 1) * BATCH * STOCH,
        hlast, zlast);
}

// Round 12
// 4675.644 us; speedup vs baseline: 2.4337x; 2.4337x over previous
//
#include <hip/hip_runtime.h>
#include <hip/hip_bf16.h>
#include <stdint.h>

#define NSTEP 64
#define BATCH 32
#define EMBED_D 1536
#define ACT_D 16
#define DETER 2048
#define STOCH 512
#define HIDDEN 1024
#define FEAT 2560
#define NBLK 256

typedef __attribute__((ext_vector_type(8))) short bf16x8;
typedef __attribute__((ext_vector_type(4))) float f32x4;

#define MFMA16 __builtin_amdgcn_mfma_f32_16x16x32_bf16
#define AGENT __HIP_MEMORY_SCOPE_AGENT

__device__ __forceinline__ float eluf(float x) { return x > 0.f ? x : expf(x) - 1.f; }
__device__ __forceinline__ float sigf(float x) { return 1.f / (1.f + expf(-x)); }
__device__ __forceinline__ unsigned short f2bf(float f) {
    __hip_bfloat16 h = __float2bfloat16(f);
    return __builtin_bit_cast(unsigned short, h);
}
__device__ __forceinline__ float bf2f(unsigned short u) {
    unsigned v = ((unsigned)u) << 16;
    return __builtin_bit_cast(float, v);
}

// ---- sc1 (agent-scope, fence-free) access helpers — r5/r7/r10 proven data plane
__device__ __forceinline__ void stc_u32(unsigned* p, unsigned v) {
    __hip_atomic_store(p, v, __ATOMIC_RELAXED, AGENT);
}
__device__ __forceinline__ void stc_u64(unsigned long long* p, unsigned long long v) {
    __hip_atomic_store(p, v, __ATOMIC_RELAXED, AGENT);
}
__device__ __forceinline__ unsigned long long ldc_u64(const unsigned long long* p) {
    return __hip_atomic_load(p, __ATOMIC_RELAXED, AGENT);
}
__device__ __forceinline__ float ldc_f32(const float* p) {
    return __hip_atomic_load(p, __ATOMIC_RELAXED, AGENT);
}
__device__ __forceinline__ int ldc_i32(const int* p) {
    return __hip_atomic_load(p, __ATOMIC_RELAXED, AGENT);
}
__device__ __forceinline__ void stc_i32(int* p, int v) {
    __hip_atomic_store(p, v, __ATOMIC_RELAXED, AGENT);
}
__device__ __forceinline__ bf16x8 ldc_bf8(const unsigned short* p) {
    union { unsigned long long q[2]; bf16x8 v; } u;
    u.q[0] = ldc_u64((const unsigned long long*)p);
    u.q[1] = ldc_u64((const unsigned long long*)(p + 4));
    return u.v;
}
__device__ __forceinline__ ushort4 ldc_us4(const unsigned short* p) {
    unsigned long long q = ldc_u64((const unsigned long long*)p);
    return __builtin_bit_cast(ushort4, q);
}

// ---- flag-tree grid barrier, 32-way replicated release (r10-verified)
__device__ __forceinline__ void gbar3(int* flags, int* release, int epoch) {
    asm volatile("s_waitcnt vmcnt(0)" ::: "memory");
    __syncthreads();
    if (blockIdx.x == 0) {
        int tid = threadIdx.x;
        if (tid >= 1 && tid < NBLK) {
            while (ldc_i32(&flags[tid * 32]) < epoch) __builtin_amdgcn_s_sleep(4);
        }
        asm volatile("" ::: "memory");
        __syncthreads();
        if (tid < 32) stc_i32(&release[tid * 32], epoch);
    } else {
        if (threadIdx.x == 0) {
            stc_i32(&flags[blockIdx.x * 32], epoch);
            int* rel = &release[(blockIdx.x & 31) * 32];
            while (ldc_i32(rel) < epoch) __builtin_amdgcn_s_sleep(4);
        }
        asm volatile("" ::: "memory");
        __syncthreads();
    }
}

// ---------------- all weight conversions in one kernel (22544384 elements, bf16)
__global__ __launch_bounds__(256) void k_cvt_all(
    const float* __restrict__ s0, unsigned short* __restrict__ d0,
    const float* __restrict__ s1, unsigned short* __restrict__ d1,
    const float* __restrict__ s2, unsigned short* __restrict__ d2,
    const float* __restrict__ s3, unsigned short* __restrict__ d3,
    const float* __restrict__ s4, unsigned short* __restrict__ d4)
{
    long long e = ((long long)blockIdx.x * 256 + threadIdx.x) * 4;
    const float* src; unsigned short* dst; long long off;
    if (e < 524288)        { src = s0; dst = d0; off = e; }
    else if (e < 6815744)  { src = s1; dst = d1; off = e - 524288; }
    else if (e < 19398656) { src = s2; dst = d2; off = e - 6815744; }
    else if (e < 21495808) { src = s3; dst = d3; off = e - 19398656; }
    else if (e < 22544384) { src = s4; dst = d4; off = e - 21495808; }
    else return;
    float4 v = *reinterpret_cast<const float4*>(src + off);
    ushort4 o;
    o.x = f2bf(v.x); o.y = f2bf(v.y); o.z = f2bf(v.z); o.w = f2bf(v.w);
    *reinterpret_cast<ushort4*>(dst + off) = o;
}

// ---------------- setup: premasked h0 (f32+bf16), premasked z0 (bf16), flags=0
__global__ __launch_bounds__(256) void k_setup(
    const float* __restrict__ h0, const float* __restrict__ z0,
    const uint8_t* __restrict__ reset0,
    float* __restrict__ h0m, unsigned short* __restrict__ h16m0,
    unsigned short* __restrict__ z16m, int* __restrict__ flags)
{
    int gid = blockIdx.x * 256 + threadIdx.x;
    int idx = gid * 4;
    if (idx < BATCH * DETER) {
        int b = idx >> 11;
        float m = reset0[b] ? 0.f : 1.f;
        float4 v = *reinterpret_cast<const float4*>(h0 + idx);
        v.x *= m; v.y *= m; v.z *= m; v.w *= m;
        *reinterpret_cast<float4*>(h0m + idx) = v;
        ushort4 o;
        o.x = f2bf(v.x); o.y = f2bf(v.y); o.z = f2bf(v.z); o.w = f2bf(v.w);
        *reinterpret_cast<ushort4*>(h16m0 + idx) = o;
    } else if (idx < BATCH * DETER + BATCH * STOCH) {
        int zi = idx - BATCH * DETER;
        int b = zi >> 9;
        float m = reset0[b] ? 0.f : 1.f;
        float4 v = *reinterpret_cast<const float4*>(z0 + zi);
        ushort4 o;
        o.x = f2bf(v.x * m); o.y = f2bf(v.y * m); o.z = f2bf(v.z * m); o.w = f2bf(v.w * m);
        *reinterpret_cast<ushort4*>(z16m + zi) = o;
    }
    if (gid < 9216) flags[gid] = 0;   // flags (8192 ints) + release (1024 ints)
}

// ---------------- preA[r][j] = b_z[j] + sum_k action[r][k]*W_a[j][k]  (K=16)
__global__ __launch_bounds__(256) void k_preA(
    const float* __restrict__ action, const float* __restrict__ Wa,
    const float* __restrict__ bz, float* __restrict__ preA)
{
    __shared__ float al[16];
    int r = blockIdx.x, t = threadIdx.x;
    if (t < 16) al[t] = action[r * 16 + t];
    __syncthreads();
#pragma unroll
    for (int c = 0; c < 4; ++c) {
        int j = t + c * 256;
        const float* wr = Wa + j * 16;
        float s = bz[j];
#pragma unroll
        for (int k = 0; k < 16; ++k) s += al[k] * wr[k];
        preA[(size_t)r * 1024 + j] = s;
    }
}

// ---------------- one-shot MFMA GEMM (f32 sources, bf16 staging)
__global__ __launch_bounds__(256) void gemm_mfma(
    const float* __restrict__ A, int lda,
    const float* __restrict__ B, int ldb,
    const float* __restrict__ bias,
    float* __restrict__ C, int ldc, int K)
{
    __shared__ unsigned short Alds[64 * 72];
    __shared__ unsigned short Blds[64 * 72];
    int t = threadIdx.x;
    int nb = blockIdx.x, mb = blockIdx.y;
    int w = t >> 6, l = t & 63, l15 = l & 15, kg = l >> 4;
    f32x4 acc[4] = {{0,0,0,0},{0,0,0,0},{0,0,0,0},{0,0,0,0}};
    int srow = t >> 2, skq = (t & 3) * 16;
    const float* Asrc = A + (size_t)(mb * 64 + srow) * lda + skq;
    const float* Bsrc = B + (size_t)(nb * 64 + srow) * ldb + skq;
    unsigned short* Adst = &Alds[srow * 72 + skq];
    unsigned short* Bdst = &Blds[srow * 72 + skq];
    for (int kt = 0; kt < K; kt += 64) {
        __syncthreads();
#pragma unroll
        for (int c = 0; c < 16; c += 4) {
            float4 va = *reinterpret_cast<const float4*>(Asrc + kt + c);
            float4 vb = *reinterpret_cast<const float4*>(Bsrc + kt + c);
            ushort4 oa, ob;
            oa.x = f2bf(va.x); oa.y = f2bf(va.y); oa.z = f2bf(va.z); oa.w = f2bf(va.w);
            ob.x = f2bf(vb.x); ob.y = f2bf(vb.y); ob.z = f2bf(vb.z); ob.w = f2bf(vb.w);
            *reinterpret_cast<ushort4*>(Adst + c) = oa;
            *reinterpret_cast<ushort4*>(Bdst + c) = ob;
        }
        __syncthreads();
#pragma unroll
        for (int ks = 0; ks < 2; ks++) {
            bf16x8 a = *reinterpret_cast<const bf16x8*>(&Alds[(w * 16 + l15) * 72 + ks * 32 + kg * 8]);
#pragma unroll
            for (int nt = 0; nt < 4; nt++) {
                bf16x8 b = *reinterpret_cast<const bf16x8*>(&Blds[(nt * 16 + l15) * 72 + ks * 32 + kg * 8]);
                acc[nt] = MFMA16(a, b, acc[nt], 0, 0, 0);
            }
        }
    }
#pragma unroll
    for (int nt = 0; nt < 4; nt++) {
        int n = nb * 64 + nt * 16 + l15;
        float bv = bias[n];
#pragma unroll
        for (int i = 0; i < 4; i++) {
            C[(size_t)(mb * 64 + w * 16 + kg * 4 + i) * ldc + n] = acc[nt][i] + bv;
        }
    }
}

// ---------------- row LN+elu in place (f32), rows of 1024
__global__ __launch_bounds__(256) void ln_elu_rows(
    float* __restrict__ X, const float* __restrict__ g, const float* __restrict__ bb)
{
    __shared__ float sbuf[256], qbuf[256];
    int r = blockIdx.x, t = threadIdx.x;
    float* row = X + (size_t)r * HIDDEN;
    float4 v = reinterpret_cast<const float4*>(row)[t];
    sbuf[t] = (v.x + v.y) + (v.z + v.w);
    qbuf[t] = (v.x * v.x + v.y * v.y) + (v.z * v.z + v.w * v.w);
    __syncthreads();
    for (int off = 128; off > 0; off >>= 1) {
        if (t < off) { sbuf[t] += sbuf[t + off]; qbuf[t] += qbuf[t + off]; }
        __syncthreads();
    }
    float mean = sbuf[0] / HIDDEN;
    float var = qbuf[0] / HIDDEN - mean * mean;
    float rstd = rsqrtf(var + 1e-5f);
    float4 gg = reinterpret_cast<const float4*>(g)[t];
    float4 bv = reinterpret_cast<const float4*>(bb)[t];
    float4 o;
    o.x = eluf((v.x - mean) * rstd * gg.x + bv.x);
    o.y = eluf((v.y - mean) * rstd * gg.y + bv.y);
    o.z = eluf((v.z - mean) * rstd * gg.z + bv.z);
    o.w = eluf((v.w - mean) * rstd * gg.w + bv.w);
    reinterpret_cast<float4*>(row)[t] = o;
}

__global__ __launch_bounds__(256) void k_copy_last(
    const float* __restrict__ feat63, const float* __restrict__ samp63,
    float* __restrict__ hlast, float* __restrict__ zlast)
{
    int i = blockIdx.x * 256 + threadIdx.x;
    if (i < BATCH * DETER) {
        int b = i / DETER, k = i % DETER;
        hlast[i] = feat63[(size_t)b * FEAT + k];
    }
    if (i < BATCH * STOCH) zlast[i] = samp63[i];
}

// ======================= persistent scan (plain launch, 1 block/CU) =======================
struct ScanArgs {
    const unsigned short *Wz16, *Wih16, *Whh16, *Wph16, *Wpo16;
    const float *bih, *bhh, *b_post;
    const float *ln_in_g, *ln_in_b, *ln_post_g, *ln_post_b;
    const float *h0m;
    const uint8_t *reset;
    const float *noises;
    float *postsPreA;
    float *priorsPreE;
    float *samples;
    float *feats;
    unsigned short *z16m, *x1b, *x2b, *h16u, *h16m0, *h16m1;
    float *x1parts, *x2parts;
    int *flags, *release;
};

__device__ __forceinline__ void ln_stats(const float* __restrict__ parts, float* stat, int tid) {
    if (tid < 32) {
        float s = 0.f, q = 0.f;
        for (int i = 0; i < 64; ++i) {
            union { unsigned long long u; float f[2]; } c;
            c.u = ldc_u64((const unsigned long long*)(parts + (size_t)(i * 32 + tid) * 2));
            s += c.f[0]; q += c.f[1];
        }
        float mean = s * (1.f / 1024.f);
        float var = q * (1.f / 1024.f) - mean * mean;
        stat[tid] = mean;
        stat[32 + tid] = rsqrtf(var + 1e-5f);
    }
}

__device__ __forceinline__ void ln_fill(unsigned short* Asm, const unsigned short* __restrict__ src,
                                        const float* __restrict__ g, const float* __restrict__ bb,
                                        const float* stat, int tid) {
    int row = tid & 31, kb = (tid >> 5) * 128;
    float mean = stat[row], rstd = stat[32 + row];
#pragma unroll 4
    for (int c = 0; c < 16; ++c) {
        int k = kb + c * 8;
        ushort4 u0 = ldc_us4(src + (size_t)row * 1024 + k);
        ushort4 u1 = ldc_us4(src + (size_t)row * 1024 + k + 4);
        float4 g0 = *reinterpret_cast<const float4*>(g + k);
        float4 g1 = *reinterpret_cast<const float4*>(g + k + 4);
        float4 b0 = *reinterpret_cast<const float4*>(bb + k);
        float4 b1 = *reinterpret_cast<const float4*>(bb + k + 4);
        ushort4 o0, o1;
        o0.x = f2bf(eluf((bf2f(u0.x) - mean) * rstd * g0.x + b0.x));
        o0.y = f2bf(eluf((bf2f(u0.y) - mean) * rstd * g0.y + b0.y));
        o0.z = f2bf(eluf((bf2f(u0.z) - mean) * rstd * g0.z + b0.z));
        o0.w = f2bf(eluf((bf2f(u0.w) - mean) * rstd * g0.w + b0.w));
        o1.x = f2bf(eluf((bf2f(u1.x) - mean) * rstd * g1.x + b1.x));
        o1.y = f2bf(eluf((bf2f(u1.y) - mean) * rstd * g1.y + b1.y));
        o1.z = f2bf(eluf((bf2f(u1.z) - mean) * rstd * g1.z + b1.z));
        o1.w = f2bf(eluf((bf2f(u1.w) - mean) * rstd * g1.w + b1.w));
        *reinterpret_cast<ushort4*>(Asm + row * 1032 + k) = o0;
        *reinterpret_cast<ushort4*>(Asm + row * 1032 + k + 4) = o1;
    }
}

__global__ __launch_bounds__(256, 1) void k_scan(ScanArgs a) {
    // 90112 B > 80 KiB forces 1 block/CU; grid 256 <= 256 CUs -> all co-resident.
    __shared__ char smem[90112];
    unsigned short* Asm = (unsigned short*)smem;       // 66048 B: 32 x 1032 bf16
    float* cbuf = (float*)(smem + 66048);              // 8 KB
    float* stat = (float*)(smem + 66048 + 8192);       // 512 B

    const int bid = blockIdx.x;
    const int tid = threadIdx.x;
    const int w = tid >> 6, l = tid & 63, l15 = l & 15, kg = l >> 4;
    int epoch = 0;

    for (int t = 0; t < NSTEP; ++t) {
        const float* preA_t = a.postsPreA + (size_t)t * 32768;
        const float* preE_t = a.priorsPreE + (size_t)t * 32768;
        float* posts_t = a.postsPreA + (size_t)t * 32768;
        float* samples_t = a.samples + (size_t)t * 16384;
        float* feats_t = a.feats + (size_t)t * 81920;
        const float* featsPrev = a.feats + (size_t)(t - 1) * 81920;
        const unsigned short* h16cur = (t & 1) ? a.h16m1 : a.h16m0;
        unsigned short* h16nxt = (t & 1) ? a.h16m0 : a.h16m1;

        // ---------- P1: x1 = preA + (m z) @ Wz^T  (64 blocks x 16 cols, bf16)
        if (bid < 64) {
            int j0 = bid * 16;
            const unsigned short* A0 = a.z16m + l15 * 512 + w * 128 + kg * 8;
            const unsigned short* A1 = A0 + 16 * 512;
            const unsigned short* Bp = a.Wz16 + (size_t)(j0 + l15) * 512 + w * 128 + kg * 8;
            f32x4 c0 = {0,0,0,0}, c1 = {0,0,0,0};
#pragma unroll
            for (int ks = 0; ks < 4; ++ks) {
                bf16x8 b = *reinterpret_cast<const bf16x8*>(Bp + ks * 32);
                c0 = MFMA16(ldc_bf8(A0 + ks * 32), b, c0, 0, 0, 0);
                c1 = MFMA16(ldc_bf8(A1 + ks * 32), b, c1, 0, 0, 0);
            }
#pragma unroll
            for (int i = 0; i < 4; ++i) {
                cbuf[w * 512 + (kg * 4 + i) * 16 + l15] = c0[i];
                cbuf[w * 512 + (16 + kg * 4 + i) * 16 + l15] = c1[i];
            }
            __syncthreads();
            int r = tid >> 3, c2 = (tid & 7) * 2;
            int base = r * 16 + c2;
            float v0 = cbuf[base] + cbuf[512 + base] + cbuf[1024 + base] + cbuf[1536 + base]
                     + preA_t[r * 1024 + j0 + c2];
            float v1 = cbuf[base + 1] + cbuf[512 + base + 1] + cbuf[1024 + base + 1] + cbuf[1536 + base + 1]
                     + preA_t[r * 1024 + j0 + c2 + 1];
            unsigned short u0 = f2bf(v0), u1 = f2bf(v1);
            stc_u32((unsigned*)(a.x1b + (size_t)r * 1024 + j0 + c2),
                    (unsigned)u0 | ((unsigned)u1 << 16));
            float w0 = bf2f(u0), w1 = bf2f(u1);
            float s = w0 + w1, q = w0 * w0 + w1 * w1;
            s += __shfl_xor(s, 1); q += __shfl_xor(q, 1);
            s += __shfl_xor(s, 2); q += __shfl_xor(q, 2);
            s += __shfl_xor(s, 4); q += __shfl_xor(q, 4);
            if ((tid & 7) == 0) {
                union { float f[2]; unsigned long long u; } pu;
                pu.f[0] = s; pu.f[1] = q;
                stc_u64((unsigned long long*)(a.x1parts + ((size_t)bid * 32 + r) * 2), pu.u);
            }
        }
        epoch++; gbar3(a.flags, a.release, epoch);

        // ---------- P2: gates MFMA + GRU combine (128 blocks x 16 h-cols)
        if (bid < 128) {
            int j0 = bid * 16;
            ln_stats(a.x1parts, stat, tid);
            __syncthreads();
            ln_fill(Asm, a.x1b, a.ln_in_g, a.ln_in_b, stat, tid);
            __syncthreads();
            bool isI = (w < 2);
            int mt = w & 1;
            f32x4 cr = {0,0,0,0}, cu = {0,0,0,0}, cn = {0,0,0,0};
            if (isI) {
                const unsigned short* ap = Asm + (mt * 16 + l15) * 1032 + kg * 8;
                const unsigned short* br = a.Wih16 + (size_t)(j0 + l15) * 1024 + kg * 8;
                const unsigned short* bu = br + (size_t)2048 * 1024;
                const unsigned short* bn = bu + (size_t)2048 * 1024;
#pragma unroll 8
                for (int ks = 0; ks < 32; ++ks) {
                    bf16x8 av = *reinterpret_cast<const bf16x8*>(ap + ks * 32);
                    cr = MFMA16(av, *reinterpret_cast<const bf16x8*>(br + ks * 32), cr, 0, 0, 0);
                    cu = MFMA16(av, *reinterpret_cast<const bf16x8*>(bu + ks * 32), cu, 0, 0, 0);
                    cn = MFMA16(av, *reinterpret_cast<const bf16x8*>(bn + ks * 32), cn, 0, 0, 0);
                }
            } else {
                const unsigned short* ap = h16cur + (size_t)(mt * 16 + l15) * 2048 + kg * 8;
                const unsigned short* br = a.Whh16 + (size_t)(j0 + l15) * 2048 + kg * 8;
                const unsigned short* bu = br + (size_t)2048 * 2048;
                const unsigned short* bn = bu + (size_t)2048 * 2048;
#pragma unroll 8
                for (int ks = 0; ks < 64; ++ks) {
                    bf16x8 av = ldc_bf8(ap + ks * 32);
                    cr = MFMA16(av, *reinterpret_cast<const bf16x8*>(br + ks * 32), cr, 0, 0, 0);
                    cu = MFMA16(av, *reinterpret_cast<const bf16x8*>(bu + ks * 32), cu, 0, 0, 0);
                    cn = MFMA16(av, *reinterpret_cast<const bf16x8*>(bn + ks * 32), cn, 0, 0, 0);
                }
#pragma unroll
                for (int i = 0; i < 4; ++i) {
                    cbuf[((mt * 3 + 0) * 16 + kg * 4 + i) * 16 + l15] = cr[i];
                    cbuf[((mt * 3 + 1) * 16 + kg * 4 + i) * 16 + l15] = cu[i];
                    cbuf[((mt * 3 + 2) * 16 + kg * 4 + i) * 16 + l15] = cn[i];
                }
            }
            __syncthreads();
            if (isI) {
                int j = j0 + l15;
                float bihr = a.bih[j], bihu = a.bih[j + 2048], bihn = a.bih[j + 4096];
                float bhhr = a.bhh[j], bhhu = a.bhh[j + 2048], bhhn = a.bhh[j + 4096];
#pragma unroll
                for (int i = 0; i < 4; ++i) {
                    int b = mt * 16 + kg * 4 + i;
                    float gr = cr[i] + bihr, gu = cu[i] + bihu, gn = cn[i] + bihn;
                    float hr = cbuf[((mt * 3 + 0) * 16 + kg * 4 + i) * 16 + l15] + bhhr;
                    float hu = cbuf[((mt * 3 + 1) * 16 + kg * 4 + i) * 16 + l15] + bhhu;
                    float hn = cbuf[((mt * 3 + 2) * 16 + kg * 4 + i) * 16 + l15] + bhhn;
                    float r = sigf(gr + hr), u = sigf(gu + hu);
                    float cand = tanhf(gn + r * hn);
                    float m = a.reset[t * 32 + b] ? 0.f : 1.f;
                    float hpv = (t == 0) ? a.h0m[b * 2048 + j]
                                         : ldc_f32(featsPrev + (size_t)b * 2560 + j);
                    float hnew = (1.f - u) * cand + u * (m * hpv);
                    cbuf[1536 + b * 16 + l15] = hnew;
                }
            }
            __syncthreads();
            {
                int b = tid >> 3, c2 = (tid & 7) * 2;
                float h0v = cbuf[1536 + b * 16 + c2], h1v = cbuf[1536 + b * 16 + c2 + 1];
                int j = j0 + c2;
                union { float f[2]; unsigned long long u; } fu;
                fu.f[0] = h0v; fu.f[1] = h1v;
                stc_u64((unsigned long long*)(feats_t + (size_t)b * 2560 + j), fu.u);
                unsigned short g0 = f2bf(h0v), g1 = f2bf(h1v);
                stc_u32((unsigned*)(a.h16u + (size_t)b * 2048 + j),
                        (unsigned)g0 | ((unsigned)g1 << 16));
                float mn = (t < 63) ? (a.reset[(t + 1) * 32 + b] ? 0.f : 1.f) : 1.f;
                unsigned short n0 = f2bf(h0v * mn), n1 = f2bf(h1v * mn);
                stc_u32((unsigned*)(h16nxt + (size_t)b * 2048 + j),
                        (unsigned)n0 | ((unsigned)n1 << 16));
            }
        }
        epoch++; gbar3(a.flags, a.release, epoch);

        // ---------- P3: x2 = preE + h @ Wph^T  (64 blocks x 16 cols)
        if (bid < 64) {
            int j0 = bid * 16;
            const unsigned short* A0 = a.h16u + l15 * 2048 + w * 512 + kg * 8;
            const unsigned short* A1 = A0 + 16 * 2048;
            const unsigned short* Bp = a.Wph16 + (size_t)(j0 + l15) * 2048 + w * 512 + kg * 8;
            f32x4 c0 = {0,0,0,0}, c1 = {0,0,0,0};
#pragma unroll 8
            for (int ks = 0; ks < 16; ++ks) {
                bf16x8 b = *reinterpret_cast<const bf16x8*>(Bp + ks * 32);
                c0 = MFMA16(ldc_bf8(A0 + ks * 32), b, c0, 0, 0, 0);
                c1 = MFMA16(ldc_bf8(A1 + ks * 32), b, c1, 0, 0, 0);
            }
#pragma unroll
            for (int i = 0; i < 4; ++i) {
                cbuf[w * 512 + (kg * 4 + i) * 16 + l15] = c0[i];
                cbuf[w * 512 + (16 + kg * 4 + i) * 16 + l15] = c1[i];
            }
            __syncthreads();
            int r = tid >> 3, c2 = (tid & 7) * 2;
            int base = r * 16 + c2;
            float v0 = cbuf[base] + cbuf[512 + base] + cbuf[1024 + base] + cbuf[1536 + base]
                     + preE_t[r * 1024 + j0 + c2];
            float v1 = cbuf[base + 1] + cbuf[512 + base + 1] + cbuf[1024 + base + 1] + cbuf[1536 + base + 1]
                     + preE_t[r * 1024 + j0 + c2 + 1];
            unsigned short u0 = f2bf(v0), u1 = f2bf(v1);
            stc_u32((unsigned*)(a.x2b + (size_t)r * 1024 + j0 + c2),
                    (unsigned)u0 | ((unsigned)u1 << 16));
            float w0 = bf2f(u0), w1 = bf2f(u1);
            float s = w0 + w1, q = w0 * w0 + w1 * w1;
            s += __shfl_xor(s, 1); q += __shfl_xor(q, 1);
            s += __shfl_xor(s, 2); q += __shfl_xor(q, 2);
            s += __shfl_xor(s, 4); q += __shfl_xor(q, 4);
            if ((tid & 7) == 0) {
                union { float f[2]; unsigned long long u; } pu;
                pu.f[0] = s; pu.f[1] = q;
                stc_u64((unsigned long long*)(a.x2parts + ((size_t)bid * 32 + r) * 2), pu.u);
            }
        }
        epoch++; gbar3(a.flags, a.release, epoch);

        // ---------- P4: post MFMA + sample  (32 blocks x 16 cols, bf16 Wpo)
        if (bid < 32) {
            int j0 = bid * 16;
            ln_stats(a.x2parts, stat, tid);
            __syncthreads();
            ln_fill(Asm, a.x2b, a.ln_post_g, a.ln_post_b, stat, tid);
            __syncthreads();
            int tile = w >> 1, mt = w & 1;
            const unsigned short* ap = Asm + (mt * 16 + l15) * 1032 + kg * 8;
            int n = (tile == 0) ? (j0 + l15) : (512 + j0 + l15);
            const unsigned short* Bp = a.Wpo16 + (size_t)n * 1024 + kg * 8;
            f32x4 c = {0,0,0,0};
#pragma unroll 8
            for (int ks = 0; ks < 32; ++ks) {
                c = MFMA16(*reinterpret_cast<const bf16x8*>(ap + ks * 32),
                           *reinterpret_cast<const bf16x8*>(Bp + ks * 32), c, 0, 0, 0);
            }
#pragma unroll
            for (int i = 0; i < 4; ++i)
                cbuf[(tile * 2 + mt) * 256 + (kg * 4 + i) * 16 + l15] = c[i];
            __syncthreads();
            int b = tid >> 3, c2 = (tid & 7) * 2;
            int j = j0 + c2;
            int ib = (b >> 4) * 256 + (b & 15) * 16;
            float pm0 = cbuf[ib + c2] + a.b_post[j];
            float pm1 = cbuf[ib + c2 + 1] + a.b_post[j + 1];
            float ps0 = cbuf[512 + ib + c2] + a.b_post[512 + j];
            float ps1 = cbuf[512 + ib + c2 + 1] + a.b_post[512 + j + 1];
            posts_t[(size_t)b * 1024 + j] = pm0;
            posts_t[(size_t)b * 1024 + j + 1] = pm1;
            posts_t[(size_t)b * 1024 + 512 + j] = ps0;
            posts_t[(size_t)b * 1024 + 512 + j + 1] = ps1;
            float sp0 = fmaxf(ps0, 0.f) + log1pf(expf(-fabsf(ps0)));
            float sp1 = fmaxf(ps1, 0.f) + log1pf(expf(-fabsf(ps1)));
            float n0v = a.noises[(size_t)t * 16384 + b * 512 + j];
            float n1v = a.noises[(size_t)t * 16384 + b * 512 + j + 1];
            float smp0 = pm0 + (sp0 + 0.1f) * n0v;
            float smp1 = pm1 + (sp1 + 0.1f) * n1v;
            samples_t[(size_t)b * 512 + j] = smp0;
            samples_t[(size_t)b * 512 + j + 1] = smp1;
            feats_t[(size_t)b * 2560 + 2048 + j] = smp0;
            feats_t[(size_t)b * 2560 + 2048 + j + 1] = smp1;
            float mn = (t < 63) ? (a.reset[(t + 1) * 32 + b] ? 0.f : 1.f) : 1.f;
            unsigned short z0_ = f2bf(smp0 * mn), z1_ = f2bf(smp1 * mn);
            stc_u32((unsigned*)(a.z16m + (size_t)b * 512 + j),
                    (unsigned)z0_ | ((unsigned)z1_ << 16));
        }
        epoch++; gbar3(a.flags, a.release, epoch);
    }
}

// ws byte offsets (r5 layout)
#define WS_WZ16   ((size_t)0)
#define WS_WIH16  ((size_t)1048576)
#define WS_WHH16  ((size_t)13631488)
#define WS_WPH16  ((size_t)38797312)
#define WS_WPO16  ((size_t)42991616)
#define WS_Z16M   ((size_t)45088768)
#define WS_H16M0  ((size_t)45121536)
#define WS_H16M1  ((size_t)45252608)
#define WS_H16U   ((size_t)45383680)
#define WS_H0M    ((size_t)45514752)
#define WS_X1B    ((size_t)45776896)
#define WS_X2B    ((size_t)45842432)
#define WS_X1P    ((size_t)45907968)
#define WS_X2P    ((size_t)45924352)
#define WS_FLAGS  ((size_t)45940736)
#define WS_REL    ((size_t)45973504)
#define WS_PRX    WS_WIH16   // alias: Wih16 dead after scan

extern "C" void kernel_launch(void* const* d_in, const int* in_sizes, int n_in,
                              void* d_out, int out_size, void* d_ws, size_t ws_size,
                              hipStream_t stream)
{
    (void)in_sizes; (void)n_in; (void)out_size; (void)ws_size;
    const float*   embed  = (const float*)d_in[0];
    const float*   action = (const float*)d_in[1];
    const uint8_t* reset  = (const uint8_t*)d_in[2];
    const float*   h0     = (const float*)d_in[3];
    const float*   z0     = (const float*)d_in[4];
    const float*   noises = (const float*)d_in[5];
    const float*   W_z    = (const float*)d_in[6];
    const float*   b_z    = (const float*)d_in[7];
    const float*   W_a    = (const float*)d_in[8];
    const float*   ln_in_g = (const float*)d_in[9];
    const float*   ln_in_b = (const float*)d_in[10];
    const float*   Wih    = (const float*)d_in[11];
    const float*   Whh    = (const float*)d_in[12];
    const float*   bih    = (const float*)d_in[13];
    const float*   bhh    = (const float*)d_in[14];
    const float*   W_ph   = (const float*)d_in[15];
    const float*   b_ph   = (const float*)d_in[16];
    const float*   W_pe   = (const float*)d_in[17];
    const float*   ln_post_g = (const float*)d_in[18];
    const float*   ln_post_b = (const float*)d_in[19];
    const float*   W_post = (const float*)d_in[20];
    const float*   b_post = (const float*)d_in[21];
    const float*   W_prh  = (const float*)d_in[22];
    const float*   b_prh  = (const float*)d_in[23];
    const float*   ln_pr_g = (const float*)d_in[24];
    const float*   ln_pr_b = (const float*)d_in[25];
    const float*   W_pr   = (const float*)d_in[26];
    const float*   b_pr   = (const float*)d_in[27];

    float* out     = (float*)d_out;
    float* priors  = out;                  // preE lives here during scan
    float* posts   = out + 2097152;        // preA lives here during scan
    float* samples = out + 4194304;
    float* feats   = out + 5242880;
    float* hlast   = out + 10485760;
    float* zlast   = out + 10551296;

    char* ws = (char*)d_ws;
    unsigned short* Wz16  = (unsigned short*)(ws + WS_WZ16);
    unsigned short* Wih16 = (unsigned short*)(ws + WS_WIH16);
    unsigned short* Whh16 = (unsigned short*)(ws + WS_WHH16);
    unsigned short* Wph16 = (unsigned short*)(ws + WS_WPH16);
    unsigned short* Wpo16 = (unsigned short*)(ws + WS_WPO16);
    unsigned short* z16m  = (unsigned short*)(ws + WS_Z16M);
    unsigned short* h16m0 = (unsigned short*)(ws + WS_H16M0);
    unsigned short* h16m1 = (unsigned short*)(ws + WS_H16M1);
    unsigned short* h16u  = (unsigned short*)(ws + WS_H16U);
    float*          h0m   = (float*)(ws + WS_H0M);
    unsigned short* x1b   = (unsigned short*)(ws + WS_X1B);
    unsigned short* x2b   = (unsigned short*)(ws + WS_X2B);
    float*          x1p   = (float*)(ws + WS_X1P);
    float*          x2p   = (float*)(ws + WS_X2P);
    int*            flags = (int*)(ws + WS_FLAGS);
    int*            release = (int*)(ws + WS_REL);
    float*          prx   = (float*)(ws + WS_PRX);

    dim3 blk(256);

    // setup
    k_cvt_all<<<dim3(22016), blk, 0, stream>>>(W_z, Wz16, Wih, Wih16, Whh, Whh16,
                                               W_ph, Wph16, W_post, Wpo16);
    k_setup<<<dim3(80), blk, 0, stream>>>(h0, z0, reset, h0m, h16m0, z16m, flags);

    // preA -> posts region ; preE -> priors region
    k_preA<<<dim3(2048), blk, 0, stream>>>(action, W_a, b_z, posts);
    gemm_mfma<<<dim3(16, 32), blk, 0, stream>>>(embed, EMBED_D, W_pe, EMBED_D, b_ph,
                                                priors, HIDDEN, EMBED_D);

    // the whole 64-step scan: one persistent kernel, plain launch
    ScanArgs sa;
    sa.Wz16 = Wz16; sa.Wih16 = Wih16; sa.Whh16 = Whh16; sa.Wph16 = Wph16; sa.Wpo16 = Wpo16;
    sa.bih = bih; sa.bhh = bhh; sa.b_post = b_post;
    sa.ln_in_g = ln_in_g; sa.ln_in_b = ln_in_b; sa.ln_post_g = ln_post_g; sa.ln_post_b = ln_post_b;
    sa.h0m = h0m; sa.reset = reset; sa.noises = noises;
    sa.postsPreA = posts; sa.priorsPreE = priors; sa.samples = samples; sa.feats = feats;
    sa.z16m = z16m; sa.x1b = x1b; sa.x2b = x2b; sa.h16u = h16u;
    sa.h16m0 = h16m0; sa.h16m1 = h16m1;
    sa.x1parts = x1p; sa.x2parts = x2p;
    sa.flags = flags; sa.release = release;
    k_scan<<<dim3(NBLK), blk, 0, stream>>>(sa);

    // prior chain
    gemm_mfma<<<dim3(16, 32), blk, 0, stream>>>(feats, FEAT, W_prh, DETER, b_prh,
                                                prx, HIDDEN, DETER);
    ln_elu_rows<<<dim3(2048), blk, 0, stream>>>(prx, ln_pr_g, ln_pr_b);
    gemm_mfma<<<dim3(16, 32), blk, 0, stream>>>(prx, HIDDEN, W_pr, HIDDEN, b_pr,
                                                priors, HIDDEN, HIDDEN);

    k_copy_last<<<dim3(256), blk, 0, stream>>>(
        feats + (size_t)(NSTEP - 1) * BATCH * FEAT,
        samples + (size_t)(NSTEP - 1) * BATCH * STOCH,
        hlast, zlast);
}